// Round 9
// baseline (198.920 us; speedup 1.0000x reference)
//
#include <hip/hip_runtime.h>
#include <hip/hip_bf16.h>

// Problem constants
#define TT   512
#define BB   32
#define TS_F 76
#define N_WF 200
#define WF_LEN 1000
#define TEXT_D 200
#define WF_D 100
#define HID  256
#define FC_H 256
#define ROWS (TT*BB)              // 16384
#define KTOT 576                  // padded total feat K (556 -> 576)

// stage-1 geometry
#define S1_NPAD 128
#define S1_Z    4
#define S1_KPS  256
#define S1T_LD  224               // padded n_wf dim of transposed partials
#define S3_KPAD 224

// feat2: ts_out cols [0,256) + spread cols [256,356) + zeros [356,376) + pad
#define FEAT2_LD 384

typedef __attribute__((ext_vector_type(8))) short short8;
typedef __attribute__((ext_vector_type(4))) short sshort4;
typedef __attribute__((ext_vector_type(4))) float f32x4;

// Truncating bf16 split (compensated s4 path: feat2 / W1)
__device__ __forceinline__ void split_bf16(float v, short& h, short& l) {
    unsigned u = __builtin_bit_cast(unsigned, v);
    unsigned hu = u & 0xFFFF0000u;
    h = (short)(hu >> 16);
    float r = v - __builtin_bit_cast(float, hu);
    l = (short)(__builtin_bit_cast(unsigned, r) >> 16);
}

// Round-half-up bf16 convert for plain-bf16 operands (s1/s2/s3)
__device__ __forceinline__ short bf16_rh(float v) {
    unsigned u = __builtin_bit_cast(unsigned, v);
    return (short)((u + 0x8000u) >> 16);
}

// ============ K1 (256 thr): s1 partials + s2 feat + W1 prep + inits ========
// blocks [0,400):      s1  64x128 tile, z = b/100; plain bf16
// blocks [400,1424):   s2  64x64 tile; plain bf16; tanh -> feat2 split store
// blocks [1424,1496):  W1 -> transposed hi/lo split [256][576]
// blocks [1496,1624):  out init (b2)
// blocks [1624,1752):  feat2 zero strip [356,376)
__global__ __launch_bounds__(256)
void k1_fused(const float* __restrict__ wf, const float* __restrict__ ts,
              const float* __restrict__ W_wf, const float* __restrict__ W_ts,
              const float* __restrict__ W1, const float* __restrict__ b_ts,
              const float* __restrict__ b2,
              float* __restrict__ partT,
              short* __restrict__ featH, short* __restrict__ featL,
              short* __restrict__ w1th, short* __restrict__ w1tl,
              float* __restrict__ out)
{
    __shared__ short smem[7680];    // s1: A 64x40 | B 128x40 ; s2: A 64x40 | B 64x40

    const int b = blockIdx.x, tid = threadIdx.x;
    const int wv = tid >> 6, lane = tid & 63;
    const int m16 = lane & 15, quad = lane >> 4, kq = quad * 8;

    short* Ah = smem;               // 64 x 40
    short* Bh = smem + 2560;        // up to 128 x 40

    if (b < 400) {
        // ---------------- s1: (wf @ W_wf)^T partials, 64 rows x 128 cols -----
        const int by = b % 100, z = b / 100;
        const int row0 = by * 64;
        const int kb = z * S1_KPS, kend = kb + S1_KPS;
        float* Cb = partT + (long long)z * (BB * S1_NPAD * S1T_LD);

        f32x4 acc[8];
        #pragma unroll
        for (int j = 0; j < 8; j++) acc[j] = f32x4{0.f, 0.f, 0.f, 0.f};

        const int ar = tid >> 2, akc = (tid & 3) * 8;

        for (int k0 = kb; k0 < kend; k0 += 32) {
            __syncthreads();
            {   // A: 64x32 wf rows, fp32 -> bf16
                int kk = k0 + akc;
                const float* ap = wf + (long long)(row0 + ar) * WF_LEN + kk;
                float v[8];
                if (kk + 8 <= WF_LEN) {
                    float4 t0 = ((const float4*)ap)[0];
                    float4 t1 = ((const float4*)ap)[1];
                    v[0]=t0.x; v[1]=t0.y; v[2]=t0.z; v[3]=t0.w;
                    v[4]=t1.x; v[5]=t1.y; v[6]=t1.z; v[7]=t1.w;
                } else {
                    #pragma unroll
                    for (int q = 0; q < 8; q++) v[q] = (kk + q < WF_LEN) ? ap[q] : 0.f;
                }
                short8 h8;
                #pragma unroll
                for (int q = 0; q < 8; q++) h8[q] = bf16_rh(v[q]);
                *(short8*)&Ah[ar * 40 + akc] = h8;
            }
            {   // B: 128x32 = W_wf^T chunk, cvt in-kernel (L2-hot)
                #pragma unroll
                for (int i = 0; i < 2; i++) {
                    int t = tid * 2 + i;
                    int c = t >> 2, kg = (t & 3) * 8;
                    short8 h8;
                    #pragma unroll
                    for (int q = 0; q < 8; q++) {
                        int k = k0 + kg + q;
                        float v = (k < WF_LEN && c < WF_D) ? W_wf[k * WF_D + c] : 0.f;
                        h8[q] = bf16_rh(v);
                    }
                    *(short8*)&Bh[c * 40 + kg] = h8;
                }
            }
            __syncthreads();

            short8 a_f = *(const short8*)&Ah[(wv * 16 + m16) * 40 + kq];
            #pragma unroll
            for (int j = 0; j < 8; j++) {
                short8 b_f = *(const short8*)&Bh[(j * 16 + m16) * 40 + kq];
                acc[j] = __builtin_amdgcn_mfma_f32_16x16x32_bf16(a_f, b_f, acc[j], 0, 0, 0);
            }
        }

        // transposed partial store (only c < 100 read downstream)
        #pragma unroll
        for (int j = 0; j < 8; j++) {
            int c = j * 16 + m16;
            if (c >= WF_D) continue;
            #pragma unroll
            for (int rr = 0; rr < 4; rr++) {
                int r = row0 + wv * 16 + quad * 4 + rr;
                int bb = r / N_WF, n = r - bb * N_WF;
                Cb[((long long)(bb * S1_NPAD + c)) * S1T_LD + n] = acc[j][rr];
            }
        }
    } else if (b < 1424) {
        // ---------------- s2: tanh(ts @ W_ts + b_ts) -> feat2[:,0:256) -------
        const int id2 = b - 400;
        const int bx = id2 & 3, by = id2 >> 2;
        const int row0 = by * 64, col0 = bx * 64;

        f32x4 acc[4];
        #pragma unroll
        for (int j = 0; j < 4; j++) acc[j] = f32x4{0.f, 0.f, 0.f, 0.f};

        const int ar = tid >> 2, akc = (tid & 3) * 8;

        for (int k0 = 0; k0 < 96; k0 += 32) {
            __syncthreads();
            {   // A: 64x32 ts rows
                int kk = k0 + akc;
                const float* ap = ts + (long long)(row0 + ar) * TS_F + kk;
                float v[8];
                if (kk + 8 <= TS_F) {
                    float4 t0 = ((const float4*)ap)[0];
                    float4 t1 = ((const float4*)ap)[1];
                    v[0]=t0.x; v[1]=t0.y; v[2]=t0.z; v[3]=t0.w;
                    v[4]=t1.x; v[5]=t1.y; v[6]=t1.z; v[7]=t1.w;
                } else {
                    #pragma unroll
                    for (int q = 0; q < 8; q++) v[q] = (kk + q < TS_F) ? ap[q] : 0.f;
                }
                short8 h8;
                #pragma unroll
                for (int q = 0; q < 8; q++) h8[q] = bf16_rh(v[q]);
                *(short8*)&Ah[ar * 40 + akc] = h8;
            }
            {   // B: 64x32 W_ts^T chunk
                int c = tid >> 2, kg = (tid & 3) * 8;
                short8 h8;
                #pragma unroll
                for (int q = 0; q < 8; q++) {
                    int k = k0 + kg + q;
                    h8[q] = bf16_rh((k < TS_F) ? W_ts[k * HID + col0 + c] : 0.f);
                }
                *(short8*)&Bh[c * 40 + kg] = h8;
            }
            __syncthreads();

            short8 a_f = *(const short8*)&Ah[(wv * 16 + m16) * 40 + kq];
            #pragma unroll
            for (int j = 0; j < 4; j++) {
                short8 b_f = *(const short8*)&Bh[(j * 16 + m16) * 40 + kq];
                acc[j] = __builtin_amdgcn_mfma_f32_16x16x32_bf16(a_f, b_f, acc[j], 0, 0, 0);
            }
        }

        #pragma unroll
        for (int j = 0; j < 4; j++) {
            int c = col0 + j * 16 + m16;
            float bv = b_ts[c];
            #pragma unroll
            for (int rr = 0; rr < 4; rr++) {
                int r = row0 + wv * 16 + quad * 4 + rr;
                float v = tanhf(acc[j][rr] + bv);
                short h, l; split_bf16(v, h, l);
                long long fo = (long long)r * FEAT2_LD + c;
                featH[fo] = h; featL[fo] = l;
            }
        }
    } else if (b < 1496) {              // W1^T hi/lo split
        int idx = (b - 1424) * 256 + tid;
        int n = idx / 72, kc = (idx % 72) * 8;
        #pragma unroll
        for (int j = 0; j < 8; j++) {
            int k = kc + j;
            float v = (k < 556) ? W1[k * FC_H + n] : 0.f;
            short h, l; split_bf16(v, h, l);
            w1th[n * KTOT + k] = h;
            w1tl[n * KTOT + k] = l;
        }
    } else if (b < 1624) {              // out init
        int idx = (b - 1496) * 256 + tid;
        out[idx] = b2[idx & 1];
    } else {                            // feat2 zero strip [356,376)
        int idx = (b - 1624) * 256 + tid;
        short* base = (idx >> 14) ? featL : featH;
        int r = idx & 16383;
        sshort4 zz = {0, 0, 0, 0};
        #pragma unroll
        for (int q = 0; q < 5; q++)
            *(sshort4*)&base[(long long)r * FEAT2_LD + 356 + q * 4] = zz;
    }
}

// ---- K3: s3 feat2[:,256:356) = (wwm[b] @ wf_out[b]) / 200, plain bf16 -----
// B-stage reduces the 4 split-K partials inline (+ b_wf). XCD-locality
// swizzle: the 16 blocks of each batch bz share one id%8 class, so that
// batch's 458 KB of partials lands in a single XCD L2.
__global__ __launch_bounds__(256)
void k3_s3(const float* __restrict__ wwm, const float* __restrict__ part,
           const float* __restrict__ b_wf,
           short* __restrict__ featH, short* __restrict__ featL)
{
    __shared__ short Ah[64][40];
    __shared__ short Bh[64][40];

    const int id = blockIdx.x, tid = threadIdx.x;
    const int wv = tid >> 6, lane = tid & 63;
    const int m16 = lane & 15, quad = lane >> 4, kq = quad * 8;

    const int g = id & 7, jj = id >> 3;           // XCD class, index within
    const int bz = g * 4 + (jj >> 4);             // 32 batches
    const int r4 = jj & 15, bx = r4 >> 3, by = r4 & 7;
    const float* A = wwm + (long long)bz * TT * N_WF;
    const long long frow0 = (long long)bz * TT;
    const int row0 = by * 64, col0 = bx * 64;

    f32x4 acc[4];
    #pragma unroll
    for (int j = 0; j < 4; j++) acc[j] = f32x4{0.f, 0.f, 0.f, 0.f};

    const int ar = tid >> 2, akc = (tid & 3) * 8;

    for (int k0 = 0; k0 < S3_KPAD; k0 += 32) {
        __syncthreads();
        {   // A: 64x32 from wwm
            int kk = k0 + akc;
            const float* ap = A + (long long)(row0 + ar) * N_WF + kk;
            float v[8];
            if (kk + 8 <= N_WF) {
                float4 t0 = ((const float4*)ap)[0];
                float4 t1 = ((const float4*)ap)[1];
                v[0]=t0.x; v[1]=t0.y; v[2]=t0.z; v[3]=t0.w;
                v[4]=t1.x; v[5]=t1.y; v[6]=t1.z; v[7]=t1.w;
            } else {
                #pragma unroll
                for (int q = 0; q < 8; q++) v[q] = (kk + q < N_WF) ? ap[q] : 0.f;
            }
            short8 h8;
            #pragma unroll
            for (int q = 0; q < 8; q++) h8[q] = bf16_rh(v[q]);
            *(short8*)&Ah[ar][akc] = h8;
        }
        {   // B: 64x32 = sum_z partT + b_wf, cvt inline
            int kk = k0 + akc;           // n index; 200 % 8 == 0 -> no straddle
            int d = col0 + ar;           // wf_d index
            short8 h8;
            if (d < WF_D && kk < N_WF) {
                float bv = b_wf[d];
                float s[8];
                #pragma unroll
                for (int q = 0; q < 8; q++) s[q] = bv;
                long long base = ((long long)(bz * S1_NPAD + d)) * S1T_LD + kk;
                #pragma unroll
                for (int z = 0; z < S1_Z; z++) {
                    const float* pp = part + (long long)z * (BB * S1_NPAD * S1T_LD) + base;
                    float4 t0 = ((const float4*)pp)[0];
                    float4 t1 = ((const float4*)pp)[1];
                    s[0]+=t0.x; s[1]+=t0.y; s[2]+=t0.z; s[3]+=t0.w;
                    s[4]+=t1.x; s[5]+=t1.y; s[6]+=t1.z; s[7]+=t1.w;
                }
                #pragma unroll
                for (int q = 0; q < 8; q++) h8[q] = bf16_rh(s[q]);
            } else {
                #pragma unroll
                for (int q = 0; q < 8; q++) h8[q] = 0;
            }
            *(short8*)&Bh[ar][akc] = h8;
        }
        __syncthreads();

        short8 a_f = *(const short8*)&Ah[wv * 16 + m16][kq];
        #pragma unroll
        for (int j = 0; j < 4; j++) {
            short8 b_f = *(const short8*)&Bh[j * 16 + m16][kq];
            acc[j] = __builtin_amdgcn_mfma_f32_16x16x32_bf16(a_f, b_f, acc[j], 0, 0, 0);
        }
    }

    #pragma unroll
    for (int j = 0; j < 4; j++) {
        int c = col0 + j * 16 + m16;
        if (c >= WF_D) continue;
        #pragma unroll
        for (int rr = 0; rr < 4; rr++) {
            int r = row0 + wv * 16 + quad * 4 + rr;
            float v = acc[j][rr] * (1.0f / N_WF);
            short h, l; split_bf16(v, h, l);
            long long fo = (frow0 + r) * (long long)FEAT2_LD + HID + c;
            featH[fo] = h; featL[fo] = l;
        }
    }
}

// ====== K4: s4 + head. 256 thr (4 waves), block = 64 rows x 128 cols =======
// 512 blocks, 48 KB LDS -> 3 blocks/CU (12 waves/CU) for latency hiding.
#define S4_NCH 18     // 576/32 K-chunks

__global__ __launch_bounds__(256)
void k4_s4head(const float* __restrict__ texts,
               const short* __restrict__ featH, const short* __restrict__ featL,
               const short* __restrict__ w1th, const short* __restrict__ w1tl,
               const float* __restrict__ b1, const float* __restrict__ W2,
               float* __restrict__ out)
{
    __shared__ short Ah[2][64][32], Al[2][64][32];
    __shared__ short Bh[2][128][32], Bl[2][128][32];

    const int tid = threadIdx.x;
    const int wv = tid >> 6, lane = tid & 63;
    const int m16 = lane & 15, quad = lane >> 4;
    const int row0 = (blockIdx.x >> 1) * 64;
    const int col0 = (blockIdx.x & 1) * 128;

    const int fsw = (quad ^ ((m16 >> 1) & 3)) * 8;

    const int ar  = tid >> 2;
    const int ag  = tid & 3;
    const int asw = (ag ^ ((ar >> 1) & 3)) * 8;
    const long long gr = row0 + ar;

    f32x4 acc[4][2];
    #pragma unroll
    for (int i = 0; i < 4; i++)
        #pragma unroll
        for (int j = 0; j < 2; j++) acc[i][j] = f32x4{0.f, 0.f, 0.f, 0.f};

    float  va[8];
    short8 fa_h, fa_l;
    short8 vb_h[2], vb_l[2];

    auto load_chunk = [&](int c) {
        int kc = c * 32 + ag * 8;
        if (kc + 8 <= TEXT_D) {             // texts (200%8==0: never straddles)
            const float4* p = (const float4*)(texts + gr * TEXT_D + kc);
            float4 t0 = p[0], t1 = p[1];
            va[0]=t0.x; va[1]=t0.y; va[2]=t0.z; va[3]=t0.w;
            va[4]=t1.x; va[5]=t1.y; va[6]=t1.z; va[7]=t1.w;
        } else {
            long long o = gr * FEAT2_LD + (kc - TEXT_D);
            fa_h = *(const short8*)(featH + o);
            fa_l = *(const short8*)(featL + o);
        }
        #pragma unroll
        for (int i = 0; i < 2; i++) {
            int t = tid * 2 + i;
            int bcol = t >> 2, bg = t & 3;
            long long bb = (long long)(col0 + bcol) * KTOT + c * 32 + bg * 8;
            vb_h[i] = *(const short8*)(w1th + bb);
            vb_l[i] = *(const short8*)(w1tl + bb);
        }
    };

    auto store_chunk = [&](int c, int buf) {
        {
            int kc = c * 32 + ag * 8;
            short8 h8, l8;
            if (kc + 8 <= TEXT_D) {
                #pragma unroll
                for (int q = 0; q < 8; q++) { short h, l; split_bf16(va[q], h, l); h8[q]=h; l8[q]=l; }
            } else { h8 = fa_h; l8 = fa_l; }
            *(short8*)&Ah[buf][ar][asw] = h8;
            *(short8*)&Al[buf][ar][asw] = l8;
        }
        #pragma unroll
        for (int i = 0; i < 2; i++) {
            int t = tid * 2 + i;
            int bcol = t >> 2, bg = t & 3;
            int s = (bg ^ ((bcol >> 1) & 3)) * 8;
            *(short8*)&Bh[buf][bcol][s] = vb_h[i];
            *(short8*)&Bl[buf][bcol][s] = vb_l[i];
        }
    };

    load_chunk(0);
    store_chunk(0, 0);
    __syncthreads();

    for (int c = 0; c < S4_NCH; c++) {
        const int buf = c & 1;
        if (c + 1 < S4_NCH) load_chunk(c + 1);

        short8 a_h[4], a_l[4];
        #pragma unroll
        for (int ri = 0; ri < 4; ri++) {
            a_h[ri] = *(const short8*)&Ah[buf][ri * 16 + m16][fsw];
            a_l[ri] = *(const short8*)&Al[buf][ri * 16 + m16][fsw];
        }
        #pragma unroll
        for (int ci = 0; ci < 2; ci++) {
            int C = wv * 32 + ci * 16 + m16;
            short8 b_h = *(const short8*)&Bh[buf][C][fsw];
            short8 b_l = *(const short8*)&Bl[buf][C][fsw];
            #pragma unroll
            for (int ri = 0; ri < 4; ri++) {
                acc[ri][ci] = __builtin_amdgcn_mfma_f32_16x16x32_bf16(a_h[ri], b_h, acc[ri][ci], 0, 0, 0);
                acc[ri][ci] = __builtin_amdgcn_mfma_f32_16x16x32_bf16(a_h[ri], b_l, acc[ri][ci], 0, 0, 0);
                acc[ri][ci] = __builtin_amdgcn_mfma_f32_16x16x32_bf16(a_l[ri], b_h, acc[ri][ci], 0, 0, 0);
            }
        }
        if (c + 1 < S4_NCH) {
            store_chunk(c + 1, buf ^ 1);
            __syncthreads();
        }
    }

    // epilogue: relu + fused head over this wave's 32 cols
    float o0[4][4] = {}, o1[4][4] = {};
    #pragma unroll
    for (int ci = 0; ci < 2; ci++) {
        int C = col0 + wv * 32 + ci * 16 + m16;
        float bv  = b1[C];
        float w20 = W2[C * 2 + 0];
        float w21 = W2[C * 2 + 1];
        #pragma unroll
        for (int ri = 0; ri < 4; ri++)
            #pragma unroll
            for (int rr = 0; rr < 4; rr++) {
                float v = fmaxf(acc[ri][ci][rr] + bv, 0.f);
                o0[ri][rr] += v * w20;
                o1[ri][rr] += v * w21;
            }
    }
    #pragma unroll
    for (int ri = 0; ri < 4; ri++)
        #pragma unroll
        for (int rr = 0; rr < 4; rr++) {
            float s0 = o0[ri][rr], s1 = o1[ri][rr];
            #pragma unroll
            for (int mk = 1; mk < 16; mk <<= 1) {
                s0 += __shfl_xor(s0, mk);
                s1 += __shfl_xor(s1, mk);
            }
            if (m16 == 0) {
                int r = row0 + ri * 16 + quad * 4 + rr;
                atomicAdd(&out[r * 2 + 0], s0);
                atomicAdd(&out[r * 2 + 1], s1);
            }
        }
}

extern "C" void kernel_launch(void* const* d_in, const int* in_sizes, int n_in,
                              void* d_out, int out_size, void* d_ws, size_t ws_size,
                              hipStream_t stream)
{
    const float* texts = (const float*)d_in[0];   // (512,32,200)
    const float* ts    = (const float*)d_in[1];   // (512,32,76)
    const float* wf    = (const float*)d_in[2];   // (32,200,1000)
    const float* wwm   = (const float*)d_in[3];   // (32,512,200)
    const float* W_wf  = (const float*)d_in[4];   // (1000,100)
    const float* b_wf  = (const float*)d_in[5];
    const float* W_ts  = (const float*)d_in[6];   // (76,256)
    const float* b_ts  = (const float*)d_in[7];
    const float* W1    = (const float*)d_in[8];   // (556,256)
    const float* b1    = (const float*)d_in[9];
    const float* W2    = (const float*)d_in[10];  // (256,2)
    const float* b2    = (const float*)d_in[11];
    float* out = (float*)d_out;

    // ---- workspace layout (all disjoint, ~40 MB) ----
    short* w1th  = (short*)d_ws;                    // 256*576
    short* w1tl  = w1th  + FC_H * KTOT;
    short* featH = w1tl  + FC_H * KTOT;             // 16384*384
    short* featL = featH + (long long)ROWS * FEAT2_LD;
    float* partT = (float*)(featL + (long long)ROWS * FEAT2_LD); // 4*917504 fp32

    // 1) s1 partials + s2 feat + W1 prep + out init + feat2 zero
    k1_fused<<<1752, 256, 0, stream>>>(wf, ts, W_wf, W_ts, W1, b_ts, b2,
                                       partT, featH, featL, w1th, w1tl, out);

    // 2) s3 -> feat2 spread cols (reduces s1 partials inline, XCD-swizzled)
    k3_s3<<<512, 256, 0, stream>>>(wwm, partT, b_wf, featH, featL);

    // 3) s4 + head (512 blocks, 3 blocks/CU)
    k4_s4head<<<512, 256, 0, stream>>>(texts, featH, featL,
                                       w1th, w1tl, b1, W2, out);
}

// Round 10
// 178.432 us; speedup vs baseline: 1.1148x; 1.1148x over previous
//
#include <hip/hip_runtime.h>
#include <hip/hip_bf16.h>

// Problem constants
#define TT   512
#define BB   32
#define TS_F 76
#define N_WF 200
#define WF_LEN 1000
#define TEXT_D 200
#define WF_D 100
#define HID  256
#define FC_H 256
#define ROWS (TT*BB)              // 16384
#define KTOT 576                  // padded total feat K (556 -> 576)

// stage-1 geometry
#define S1_NPAD 128
#define S1_Z    4
#define S1_KPS  256
#define S1T_LD  224               // padded n_wf dim of transposed wf_out
#define S2_KPAD 96
#define S3_KPAD 224

// feat2: ts_out cols [0,256) + spread cols [256,356) + zeros [356,376) + pad
#define FEAT2_LD 384

typedef __attribute__((ext_vector_type(8))) short short8;
typedef __attribute__((ext_vector_type(4))) short sshort4;
typedef __attribute__((ext_vector_type(4))) float f32x4;

// Truncating bf16 split: hi = v low-16-zeroed (exact subtraction), lo = residual.
// Measured equivalent accuracy to RNE split here (absmax 0.0078125, R7-R9),
// ~4 VALU ops vs ~13.
__device__ __forceinline__ void split_bf16(float v, short& h, short& l) {
    unsigned u = __builtin_bit_cast(unsigned, v);
    unsigned hu = u & 0xFFFF0000u;
    h = (short)(hu >> 16);
    float r = v - __builtin_bit_cast(float, hu);
    l = (short)(__builtin_bit_cast(unsigned, r) >> 16);
}

// ============ K1: s1 partials + s2 feat + W1 prep + inits ==================
// blocks [0,400):      s1  (64x128 tile, split-K z = b/100, W_wf split in-kernel)
// blocks [400,1424):   s2  feat2[:,0:256) = tanh(ts @ W_ts + b_ts), W_ts in-kernel
// blocks [1424,1496):  W1 -> transposed split [256][576]
// blocks [1496,1624):  out init (b2)
// blocks [1624,1752):  feat2 zero strip [356,376)
__global__ __launch_bounds__(256)
void k1_fused(const float* __restrict__ wf, const float* __restrict__ ts,
              const float* __restrict__ W_wf, const float* __restrict__ W_ts,
              const float* __restrict__ W1, const float* __restrict__ b_ts,
              const float* __restrict__ b2,
              float* __restrict__ partT,
              short* __restrict__ featH, short* __restrict__ featL,
              short* __restrict__ w1th, short* __restrict__ w1tl,
              float* __restrict__ out)
{
    __shared__ short smem[15360];   // s1: Ah|Al 64x40, Bh|Bl 128x40; s2: Bh|Bl 64x40

    const int b = blockIdx.x, tid = threadIdx.x;
    const int wv = tid >> 6, lane = tid & 63;
    const int m16 = lane & 15, quad = lane >> 4, kq = quad * 8;

    short* Ah = smem;                 // 64x40
    short* Al = smem + 2560;
    short* Bh = smem + 5120;          // up to 128x40
    short* Bl = smem + 10240;

    if (b < 400) {
        // ---------------- s1 (compensated) ----------------
        const int by = b % 100, z = b / 100;
        const int row0 = by * 64;
        const int kb = z * S1_KPS, kend = kb + S1_KPS;
        float* Cb = partT + (long long)z * (BB * S1_NPAD * S1T_LD);

        f32x4 acc[8];
        #pragma unroll
        for (int j = 0; j < 8; j++) acc[j] = f32x4{0.f, 0.f, 0.f, 0.f};

        const int ar = tid >> 2, akc = (tid & 3) * 8;

        for (int k0 = kb; k0 < kend; k0 += 32) {
            __syncthreads();
            {   // A: 64x32 fp32 -> split
                int kk = k0 + akc;
                const float* ap = wf + (long long)(row0 + ar) * WF_LEN + kk;
                float v[8];
                if (kk + 8 <= WF_LEN) {
                    float4 t0 = ((const float4*)ap)[0];
                    float4 t1 = ((const float4*)ap)[1];
                    v[0]=t0.x; v[1]=t0.y; v[2]=t0.z; v[3]=t0.w;
                    v[4]=t1.x; v[5]=t1.y; v[6]=t1.z; v[7]=t1.w;
                } else {
                    #pragma unroll
                    for (int q = 0; q < 8; q++) v[q] = (kk + q < WF_LEN) ? ap[q] : 0.f;
                }
                short8 h8, l8;
                #pragma unroll
                for (int q = 0; q < 8; q++) { short h, l; split_bf16(v[q], h, l); h8[q]=h; l8[q]=l; }
                *(short8*)&Ah[ar * 40 + akc] = h8;
                *(short8*)&Al[ar * 40 + akc] = l8;
            }
            {   // B: 128x32 = W_wf^T chunk, split in-kernel (W_wf is L2-hot)
                #pragma unroll
                for (int i = 0; i < 2; i++) {
                    int t = tid * 2 + i;
                    int c = t >> 2, kg = (t & 3) * 8;
                    float v[8];
                    #pragma unroll
                    for (int q = 0; q < 8; q++) {
                        int k = k0 + kg + q;
                        v[q] = (k < WF_LEN && c < WF_D) ? W_wf[k * WF_D + c] : 0.f;
                    }
                    short8 h8, l8;
                    #pragma unroll
                    for (int q = 0; q < 8; q++) { short h, l; split_bf16(v[q], h, l); h8[q]=h; l8[q]=l; }
                    *(short8*)&Bh[c * 40 + kg] = h8;
                    *(short8*)&Bl[c * 40 + kg] = l8;
                }
            }
            __syncthreads();

            short8 a_h = *(const short8*)&Ah[(wv * 16 + m16) * 40 + kq];
            short8 a_l = *(const short8*)&Al[(wv * 16 + m16) * 40 + kq];
            #pragma unroll
            for (int j = 0; j < 8; j++) {
                short8 b_h = *(const short8*)&Bh[(j * 16 + m16) * 40 + kq];
                short8 b_l = *(const short8*)&Bl[(j * 16 + m16) * 40 + kq];
                acc[j] = __builtin_amdgcn_mfma_f32_16x16x32_bf16(a_h, b_h, acc[j], 0, 0, 0);
                acc[j] = __builtin_amdgcn_mfma_f32_16x16x32_bf16(a_h, b_l, acc[j], 0, 0, 0);
                acc[j] = __builtin_amdgcn_mfma_f32_16x16x32_bf16(a_l, b_h, acc[j], 0, 0, 0);
            }
        }

        // transposed partial store; c >= 100 never read by k2 (guarded there)
        #pragma unroll
        for (int j = 0; j < 8; j++) {
            int c = j * 16 + m16;
            if (c >= WF_D) continue;
            #pragma unroll
            for (int rr = 0; rr < 4; rr++) {
                int r = row0 + wv * 16 + quad * 4 + rr;
                int bb = r / N_WF, n = r - bb * N_WF;
                Cb[((long long)(bb * S1_NPAD + c)) * S1T_LD + n] = acc[j][rr];
            }
        }
    } else if (b < 1424) {
        // ---------------- s2 (compensated) ----------------
        const int id2 = b - 400;
        const int bx = id2 & 3, by = id2 >> 2;
        const int row0 = by * 64, col0 = bx * 64;

        f32x4 acc[4];
        #pragma unroll
        for (int j = 0; j < 4; j++) acc[j] = f32x4{0.f, 0.f, 0.f, 0.f};

        const int ar = tid >> 2, akc = (tid & 3) * 8;

        for (int k0 = 0; k0 < S2_KPAD; k0 += 32) {
            __syncthreads();
            {   // A: 64x32 from ts
                int kk = k0 + akc;
                const float* ap = ts + (long long)(row0 + ar) * TS_F + kk;
                float v[8];
                if (kk + 8 <= TS_F) {
                    float4 t0 = ((const float4*)ap)[0];
                    float4 t1 = ((const float4*)ap)[1];
                    v[0]=t0.x; v[1]=t0.y; v[2]=t0.z; v[3]=t0.w;
                    v[4]=t1.x; v[5]=t1.y; v[6]=t1.z; v[7]=t1.w;
                } else {
                    #pragma unroll
                    for (int q = 0; q < 8; q++) v[q] = (kk + q < TS_F) ? ap[q] : 0.f;
                }
                short8 h8, l8;
                #pragma unroll
                for (int q = 0; q < 8; q++) { short h, l; split_bf16(v[q], h, l); h8[q]=h; l8[q]=l; }
                *(short8*)&Ah[ar * 40 + akc] = h8;
                *(short8*)&Al[ar * 40 + akc] = l8;
            }
            {   // B: 64x32 = W_ts^T chunk, split in-kernel
                int c = tid >> 2, kg = (tid & 3) * 8;
                float v[8];
                #pragma unroll
                for (int q = 0; q < 8; q++) {
                    int k = k0 + kg + q;
                    v[q] = (k < TS_F) ? W_ts[k * HID + col0 + c] : 0.f;
                }
                short8 h8, l8;
                #pragma unroll
                for (int q = 0; q < 8; q++) { short h, l; split_bf16(v[q], h, l); h8[q]=h; l8[q]=l; }
                *(short8*)&Bh[c * 40 + kg] = h8;
                *(short8*)&Bl[c * 40 + kg] = l8;
            }
            __syncthreads();

            short8 a_h = *(const short8*)&Ah[(wv * 16 + m16) * 40 + kq];
            short8 a_l = *(const short8*)&Al[(wv * 16 + m16) * 40 + kq];
            #pragma unroll
            for (int j = 0; j < 4; j++) {
                short8 b_h = *(const short8*)&Bh[(j * 16 + m16) * 40 + kq];
                short8 b_l = *(const short8*)&Bl[(j * 16 + m16) * 40 + kq];
                acc[j] = __builtin_amdgcn_mfma_f32_16x16x32_bf16(a_h, b_h, acc[j], 0, 0, 0);
                acc[j] = __builtin_amdgcn_mfma_f32_16x16x32_bf16(a_h, b_l, acc[j], 0, 0, 0);
                acc[j] = __builtin_amdgcn_mfma_f32_16x16x32_bf16(a_l, b_h, acc[j], 0, 0, 0);
            }
        }

        #pragma unroll
        for (int j = 0; j < 4; j++) {
            int c = col0 + j * 16 + m16;
            #pragma unroll
            for (int rr = 0; rr < 4; rr++) {
                int r = row0 + wv * 16 + quad * 4 + rr;
                float v = tanhf(acc[j][rr] + b_ts[c]);
                short h, l; split_bf16(v, h, l);
                long long fo = (long long)r * FEAT2_LD + c;
                featH[fo] = h; featL[fo] = l;
            }
        }
    } else if (b < 1496) {              // W1^T split
        int idx = (b - 1424) * 256 + tid;
        int n = idx / 72, kc = (idx % 72) * 8;
        #pragma unroll
        for (int j = 0; j < 8; j++) {
            int k = kc + j;
            float v = (k < 556) ? W1[k * FC_H + n] : 0.f;
            short h, l; split_bf16(v, h, l);
            w1th[n * KTOT + k] = h;
            w1tl[n * KTOT + k] = l;
        }
    } else if (b < 1624) {              // out init
        int idx = (b - 1496) * 256 + tid;
        out[idx] = b2[idx & 1];
    } else {                            // feat2 zero strip [356,376)
        int idx = (b - 1624) * 256 + tid;
        short* base = (idx >> 14) ? featL : featH;
        int r = idx & 16383;
        sshort4 zz = {0, 0, 0, 0};
        #pragma unroll
        for (int q = 0; q < 5; q++)
            *(sshort4*)&base[(long long)r * FEAT2_LD + 356 + q * 4] = zz;
    }
}

// ---- K2: wf_outT hi/lo [b][128][224] = sum_z partT + b_wf -----------------
__global__ __launch_bounds__(256)
void k2_reduce(const float* __restrict__ part, const float* __restrict__ b_wf,
               short* __restrict__ oh, short* __restrict__ ol)
{
    int idx = blockIdx.x * 256 + threadIdx.x;      // exact: 917504 = 3584*256
    int rem = idx % (S1_NPAD * S1T_LD);
    int d = rem / S1T_LD, n = rem % S1T_LD;
    float s = 0.f;
    if (d < WF_D && n < N_WF) {
        s = b_wf[d];
        #pragma unroll
        for (int z = 0; z < S1_Z; z++)
            s += part[(long long)z * (BB * S1_NPAD * S1T_LD) + idx];
    }
    short h, l; split_bf16(s, h, l);
    oh[idx] = h; ol[idx] = l;
}

// ---- K3: s3 feat2[:,256:356) = (wwm[b] @ wf_out[b]) / 200 -----------------
__global__ __launch_bounds__(256)
void k3_s3(const float* __restrict__ wwm,
           const short* __restrict__ wfoTh, const short* __restrict__ wfoTl,
           short* __restrict__ featH, short* __restrict__ featL)
{
    __shared__ short Ah[64][40], Al[64][40];
    __shared__ short Bh[64][40], Bl[64][40];

    const int id = blockIdx.x, tid = threadIdx.x;
    const int wv = tid >> 6, lane = tid & 63;
    const int m16 = lane & 15, quad = lane >> 4, kq = quad * 8;

    const int bz = id >> 4, r4 = id & 15, bx = r4 >> 3, by = r4 & 7;
    const float* A = wwm + (long long)bz * TT * N_WF;
    const short* BhB = wfoTh + (long long)bz * S1_NPAD * S1T_LD;
    const short* BlB = wfoTl + (long long)bz * S1_NPAD * S1T_LD;
    const long long frow0 = (long long)bz * TT;
    const int row0 = by * 64, col0 = bx * 64;

    f32x4 acc[4];
    #pragma unroll
    for (int j = 0; j < 4; j++) acc[j] = f32x4{0.f, 0.f, 0.f, 0.f};

    const int ar = tid >> 2, akc = (tid & 3) * 8;

    for (int k0 = 0; k0 < S3_KPAD; k0 += 32) {
        __syncthreads();
        {   // A: 64x32 from wwm
            int kk = k0 + akc;
            const float* ap = A + (long long)(row0 + ar) * N_WF + kk;
            float v[8];
            if (kk + 8 <= N_WF) {
                float4 t0 = ((const float4*)ap)[0];
                float4 t1 = ((const float4*)ap)[1];
                v[0]=t0.x; v[1]=t0.y; v[2]=t0.z; v[3]=t0.w;
                v[4]=t1.x; v[5]=t1.y; v[6]=t1.z; v[7]=t1.w;
            } else {
                #pragma unroll
                for (int q = 0; q < 8; q++) v[q] = (kk + q < N_WF) ? ap[q] : 0.f;
            }
            short8 h8, l8;
            #pragma unroll
            for (int q = 0; q < 8; q++) { short h, l; split_bf16(v[q], h, l); h8[q]=h; l8[q]=l; }
            *(short8*)&Ah[ar][akc] = h8;
            *(short8*)&Al[ar][akc] = l8;
        }
        {   // B: 64x32 pre-split wf_outT
            long long off = (long long)(col0 + ar) * S1T_LD + k0 + akc;
            *(short8*)&Bh[ar][akc] = *(const short8*)(BhB + off);
            *(short8*)&Bl[ar][akc] = *(const short8*)(BlB + off);
        }
        __syncthreads();

        short8 a_h = *(const short8*)&Ah[wv * 16 + m16][kq];
        short8 a_l = *(const short8*)&Al[wv * 16 + m16][kq];
        #pragma unroll
        for (int j = 0; j < 4; j++) {
            short8 b_h = *(const short8*)&Bh[j * 16 + m16][kq];
            short8 b_l = *(const short8*)&Bl[j * 16 + m16][kq];
            acc[j] = __builtin_amdgcn_mfma_f32_16x16x32_bf16(a_h, b_h, acc[j], 0, 0, 0);
            acc[j] = __builtin_amdgcn_mfma_f32_16x16x32_bf16(a_h, b_l, acc[j], 0, 0, 0);
            acc[j] = __builtin_amdgcn_mfma_f32_16x16x32_bf16(a_l, b_h, acc[j], 0, 0, 0);
        }
    }

    #pragma unroll
    for (int j = 0; j < 4; j++) {
        int c = col0 + j * 16 + m16;
        if (c >= WF_D) continue;
        #pragma unroll
        for (int rr = 0; rr < 4; rr++) {
            int r = row0 + wv * 16 + quad * 4 + rr;
            float v = acc[j][rr] * (1.0f / N_WF);
            short h, l; split_bf16(v, h, l);
            long long fo = (frow0 + r) * (long long)FEAT2_LD + HID + c;
            featH[fo] = h; featL[fo] = l;
        }
    }
}

// ====== K4: s4 + head, 512 threads (8 waves), wave = 64 rows x 32 cols =====
#define S4_NCH 18     // 576/32 K-chunks

__global__ __launch_bounds__(512)
void k4_s4head(const float* __restrict__ texts,
               const short* __restrict__ featH, const short* __restrict__ featL,
               const short* __restrict__ w1th, const short* __restrict__ w1tl,
               const float* __restrict__ b1, const float* __restrict__ W2,
               float* __restrict__ out)
{
    __shared__ short Ah[2][64][32], Al[2][64][32];
    __shared__ short Bh[2][256][32], Bl[2][256][32];

    const int tid = threadIdx.x;
    const int wv = tid >> 6, lane = tid & 63;
    const int m16 = lane & 15, quad = lane >> 4;
    const int row0 = blockIdx.x * 64;

    const int fsw = (quad ^ ((m16 >> 1) & 3)) * 8;

    // A staging (tid < 256): one (h,l) short8 pair
    const int ar  = tid >> 2;
    const int ag  = tid & 3;
    const int asw = (ag ^ ((ar >> 1) & 3)) * 8;
    const long long gr = row0 + ar;

    f32x4 acc[4][2];
    #pragma unroll
    for (int i = 0; i < 4; i++)
        #pragma unroll
        for (int j = 0; j < 2; j++) acc[i][j] = f32x4{0.f, 0.f, 0.f, 0.f};

    float  va[8];
    short8 fa_h, fa_l;
    short8 vb_h[2], vb_l[2];

    auto load_chunk = [&](int c) {
        if (tid < 256) {
            int kc = c * 32 + ag * 8;
            if (kc + 8 <= TEXT_D) {             // texts (200%8==0: never straddles)
                const float4* p = (const float4*)(texts + gr * TEXT_D + kc);
                float4 t0 = p[0], t1 = p[1];
                va[0]=t0.x; va[1]=t0.y; va[2]=t0.z; va[3]=t0.w;
                va[4]=t1.x; va[5]=t1.y; va[6]=t1.z; va[7]=t1.w;
            } else {
                long long o = gr * FEAT2_LD + (kc - TEXT_D);
                fa_h = *(const short8*)(featH + o);
                fa_l = *(const short8*)(featL + o);
            }
        }
        #pragma unroll
        for (int i = 0; i < 2; i++) {
            int t = tid * 2 + i;
            int bcol = t >> 2, bg = t & 3;
            long long bb = (long long)bcol * KTOT + c * 32 + bg * 8;
            vb_h[i] = *(const short8*)(w1th + bb);
            vb_l[i] = *(const short8*)(w1tl + bb);
        }
    };

    auto store_chunk = [&](int c, int buf) {
        if (tid < 256) {
            int kc = c * 32 + ag * 8;
            short8 h8, l8;
            if (kc + 8 <= TEXT_D) {
                #pragma unroll
                for (int q = 0; q < 8; q++) { short h, l; split_bf16(va[q], h, l); h8[q]=h; l8[q]=l; }
            } else { h8 = fa_h; l8 = fa_l; }
            *(short8*)&Ah[buf][ar][asw] = h8;
            *(short8*)&Al[buf][ar][asw] = l8;
        }
        #pragma unroll
        for (int i = 0; i < 2; i++) {
            int t = tid * 2 + i;
            int bcol = t >> 2, bg = t & 3;
            int s = (bg ^ ((bcol >> 1) & 3)) * 8;
            *(short8*)&Bh[buf][bcol][s] = vb_h[i];
            *(short8*)&Bl[buf][bcol][s] = vb_l[i];
        }
    };

    load_chunk(0);
    store_chunk(0, 0);
    __syncthreads();

    for (int c = 0; c < S4_NCH; c++) {
        const int buf = c & 1;
        if (c + 1 < S4_NCH) load_chunk(c + 1);

        short8 a_h[4], a_l[4];
        #pragma unroll
        for (int ri = 0; ri < 4; ri++) {
            a_h[ri] = *(const short8*)&Ah[buf][ri * 16 + m16][fsw];
            a_l[ri] = *(const short8*)&Al[buf][ri * 16 + m16][fsw];
        }
        #pragma unroll
        for (int ci = 0; ci < 2; ci++) {
            int C = wv * 32 + ci * 16 + m16;
            short8 b_h = *(const short8*)&Bh[buf][C][fsw];
            short8 b_l = *(const short8*)&Bl[buf][C][fsw];
            #pragma unroll
            for (int ri = 0; ri < 4; ri++) {
                acc[ri][ci] = __builtin_amdgcn_mfma_f32_16x16x32_bf16(a_h[ri], b_h, acc[ri][ci], 0, 0, 0);
                acc[ri][ci] = __builtin_amdgcn_mfma_f32_16x16x32_bf16(a_h[ri], b_l, acc[ri][ci], 0, 0, 0);
                acc[ri][ci] = __builtin_amdgcn_mfma_f32_16x16x32_bf16(a_l[ri], b_h, acc[ri][ci], 0, 0, 0);
            }
        }
        if (c + 1 < S4_NCH) {
            store_chunk(c + 1, buf ^ 1);
            __syncthreads();
        }
    }

    // epilogue: relu + fused head over this wave's 32 cols
    float o0[4][4] = {}, o1[4][4] = {};
    #pragma unroll
    for (int ci = 0; ci < 2; ci++) {
        int C = wv * 32 + ci * 16 + m16;
        float bv  = b1[C];
        float w20 = W2[C * 2 + 0];
        float w21 = W2[C * 2 + 1];
        #pragma unroll
        for (int ri = 0; ri < 4; ri++)
            #pragma unroll
            for (int rr = 0; rr < 4; rr++) {
                float v = fmaxf(acc[ri][ci][rr] + bv, 0.f);
                o0[ri][rr] += v * w20;
                o1[ri][rr] += v * w21;
            }
    }
    #pragma unroll
    for (int ri = 0; ri < 4; ri++)
        #pragma unroll
        for (int rr = 0; rr < 4; rr++) {
            float s0 = o0[ri][rr], s1 = o1[ri][rr];
            #pragma unroll
            for (int mk = 1; mk < 16; mk <<= 1) {
                s0 += __shfl_xor(s0, mk);
                s1 += __shfl_xor(s1, mk);
            }
            if (m16 == 0) {
                int r = row0 + ri * 16 + quad * 4 + rr;
                atomicAdd(&out[r * 2 + 0], s0);
                atomicAdd(&out[r * 2 + 1], s1);
            }
        }
}

extern "C" void kernel_launch(void* const* d_in, const int* in_sizes, int n_in,
                              void* d_out, int out_size, void* d_ws, size_t ws_size,
                              hipStream_t stream)
{
    const float* texts = (const float*)d_in[0];   // (512,32,200)
    const float* ts    = (const float*)d_in[1];   // (512,32,76)
    const float* wf    = (const float*)d_in[2];   // (32,200,1000)
    const float* wwm   = (const float*)d_in[3];   // (32,512,200)
    const float* W_wf  = (const float*)d_in[4];   // (1000,100)
    const float* b_wf  = (const float*)d_in[5];
    const float* W_ts  = (const float*)d_in[6];   // (76,256)
    const float* b_ts  = (const float*)d_in[7];
    const float* W1    = (const float*)d_in[8];   // (556,256)
    const float* b1    = (const float*)d_in[9];
    const float* W2    = (const float*)d_in[10];  // (256,2)
    const float* b2    = (const float*)d_in[11];
    float* out = (float*)d_out;

    // ---- workspace layout (all disjoint, ~41 MB) ----
    short* w1th  = (short*)d_ws;                    // 256*576
    short* w1tl  = w1th  + FC_H * KTOT;
    short* wfoTh = w1tl  + FC_H * KTOT;             // 32*128*224
    short* wfoTl = wfoTh + BB * S1_NPAD * S1T_LD;
    short* featH = wfoTl + BB * S1_NPAD * S1T_LD;   // 16384*384
    short* featL = featH + (long long)ROWS * FEAT2_LD;
    float* partT = (float*)(featL + (long long)ROWS * FEAT2_LD); // 4*917504 fp32

    // 1) s1 partials + s2 feat + W1 prep + out init + feat2 zero
    k1_fused<<<1752, 256, 0, stream>>>(wf, ts, W_wf, W_ts, W1, b_ts, b2,
                                       partT, featH, featL, w1th, w1tl, out);

    // 2) reduce + split -> wf_out^T
    k2_reduce<<<3584, 256, 0, stream>>>(partT, b_wf, wfoTh, wfoTl);

    // 3) s2/s3 spread cols -> feat2
    k3_s3<<<512, 256, 0, stream>>>(wwm, wfoTh, wfoTl, featH, featL);

    // 4) s4 + head (8 waves/block)
    k4_s4head<<<ROWS / 64, 512, 0, stream>>>(texts, featH, featL,
                                             w1th, w1tl, b1, W2, out);
}